// Round 3
// baseline (311.641 us; speedup 1.0000x reference)
//
#include <hip/hip_runtime.h>

// BatchAdaptiveConv2d via implicit GEMM on bf16 MFMA.
// out[b,o,y,x] = sum_{i,dy,dx} x[b,i,y+dy-1,x+dx-1] * W[i,o,dy,dx]*wadapt[b,i]
//               + bias[o]*badapt[b,o]
// R5 = R4 resubmitted (R4 hit GPUAcquisitionTimeout; never benched).
//  - slot off-by-one fixed vs R3 (read slot (orow+dy)%10, was +1).
//  - 512-thread blocks (8 waves), 32-row tile, 10-slot rolling window:
//    16 waves/CU instead of 8, half the barriers per row.
//  - T14 async-STAGE: next 8 rows' global loads issued one full compute
//    phase early into 32 regs; ds_write after the post-compute barrier.
//    Staging barrier is raw s_barrier + lgkmcnt(0) (NOT __syncthreads) so
//    prefetch loads stay in flight across it.
//  - Weights in LDS: wbuf[tap][ot][lane][8] = lane-consecutive 16B ->
//    conflict-free ds_read_b128 per tap. Fits 128-VGPR budget, 4 waves/SIMD.

#define B_    16
#define CIN   32
#define COUT  32
#define H_    256
#define W_    256
#define EMB2  512

#define XPX   66               // 64 + 2 halo pixels per LDS row
#define PXS   32               // ushorts per pixel (32 ch * bf16)
#define ROWS_ (XPX*PXS)        // 2112 ushorts per row-slot
#define NSLOT 10               // rolling window slots (compute reads 10 rows)

using short8  = __attribute__((ext_vector_type(8))) short;
using float4v = __attribute__((ext_vector_type(4))) float;

__device__ __forceinline__ unsigned short f2bf(float f) {
    unsigned u = __builtin_bit_cast(unsigned, f);
    u += 0x7FFFu + ((u >> 16) & 1u);      // RNE
    return (unsigned short)(u >> 16);
}
__device__ __forceinline__ unsigned pk2(float a, float b) {
    return (unsigned)f2bf(a) | ((unsigned)f2bf(b) << 16);
}

// ---------------- kernel 1: adapt coefficients ----------------
// ws[0..511] = wadapt[b][i]; ws[512..1023] = bias[o]*badapt[b][o]
__global__ __launch_bounds__(256) void adapt_kernel(
    const float* __restrict__ cond, const float* __restrict__ lpe,
    const float* __restrict__ wa_w, const float* __restrict__ wa_b,
    const float* __restrict__ ba_w, const float* __restrict__ ba_b,
    const float* __restrict__ bias, float* __restrict__ ws)
{
    __shared__ float iv[EMB2];
    __shared__ float partial[64][4];
    const int b = blockIdx.x;
    const int t = threadIdx.x;

    iv[t]       = cond[b*256 + t];
    iv[t + 256] = lpe[b*256 + t];
    __syncthreads();

    const int out  = t & 63;
    const int part = t >> 6;
    const float* row = (out < 32) ? (wa_w + out*EMB2) : (ba_w + (out-32)*EMB2);
    float s = 0.f;
    #pragma unroll 8
    for (int j = part*128; j < part*128 + 128; ++j) s += iv[j] * row[j];
    partial[out][part] = s;
    __syncthreads();

    if (t < 64) {
        float v = partial[t][0] + partial[t][1] + partial[t][2] + partial[t][3];
        if (t < 32) ws[b*32 + t] = v + wa_b[t];
        else {
            int o = t - 32;
            ws[512 + b*32 + o] = bias[o] * (v + ba_b[o]);
        }
    }
}

// ---------------- kernel 2: MFMA conv ----------------
// grid (W/64, H/32, B); block 512 = 8 waves. Wave w handles output row 8t+w.
__global__ __launch_bounds__(512, 4) void conv_kernel(
    const float* __restrict__ x, const float* __restrict__ weights,
    const float* __restrict__ ws, float* __restrict__ out)
{
    __shared__ __align__(16) unsigned short xbuf[NSLOT * ROWS_];   // 42240 B
    __shared__ __align__(16) unsigned short wbuf[9 * 2 * 64 * 8];  // 18432 B

    const int tid    = threadIdx.x;
    const int lane   = tid & 63;
    const int w      = tid >> 6;        // wave 0..7
    const int ln15   = lane & 15;
    const int kg     = lane >> 4;       // k-group 0..3
    const int xstrip = blockIdx.x * 64;
    const int ystrip = blockIdx.y * 32;
    const int b      = blockIdx.z;

    // ---- scaled weights -> wbuf[tap][ot][lane][j]: lane-consecutive 16B,
    //      conflict-free ds_read_b128 per (tap,ot). 18 scalar writes/thread.
    for (int idx = tid; idx < CIN*COUT*9; idx += 512) {
        int i   = idx / 288;
        int rem = idx - i*288;
        int o   = rem / 9;
        int tap = rem - o*9;
        float v = weights[idx] * ws[b*32 + i];
        wbuf[((tap*2 + (o>>4))*64 + ((i>>3)*16 + (o&15)))*8 + (i&7)] = f2bf(v);
    }

    // ---- helpers ----
    auto load8 = [&](int g, int yy, int xx, float (&f)[8]) {
        if (((unsigned)yy < 256u) & ((unsigned)xx < 256u)) {
            const float* src = x + (((size_t)(b*CIN + g*8) << 16) + (yy << 8) + xx);
            #pragma unroll
            for (int j = 0; j < 8; ++j) f[j] = src[(size_t)j << 16];
        } else {
            #pragma unroll
            for (int j = 0; j < 8; ++j) f[j] = 0.f;
        }
    };
    auto packwrite = [&](int r, int p, int g, const float (&f)[8]) {
        unsigned slot = (unsigned)(r + 1) % NSLOT;
        unsigned dst  = slot*ROWS_ + p*PXS + ((g ^ ((p >> 1) & 3)) * 8);
        uint4 pk;
        pk.x = pk2(f[0], f[1]); pk.y = pk2(f[2], f[3]);
        pk.z = pk2(f[4], f[5]); pk.w = pk2(f[6], f[7]);
        *(uint4*)&xbuf[dst] = pk;
    };

    // ---- prologue stage rows -1..8 direct (slots 0..9) ----
    // main pixels: 10 rows * 4 groups * 64 px = 2560 chunks = 5/thread
    #pragma unroll
    for (int k = 0; k < 5; ++k) {
        int ci = tid + k*512;
        int pm = ci & 63, t2 = ci >> 6;
        int g = t2 & 3, rr = t2 >> 2;          // rr 0..9
        float f[8];
        load8(g, ystrip + rr - 1, xstrip + pm, f);
        packwrite(rr - 1, pm + 1, g, f);
    }
    // halo pixels p in {0,65}: 10 rows * 4 groups * 2 = 80 chunks
    if (tid < 80) {
        int side = tid & 1, t2 = tid >> 1;
        int g = t2 & 3, rr = t2 >> 2;
        int p = side ? 65 : 0;
        float f[8];
        load8(g, ystrip + rr - 1, xstrip + p - 1, f);
        packwrite(rr - 1, p, g, f);
    }

    // ---- per-lane modulated bias (out = ot*16 + kg*4 + r) ----
    float bm[2][4];
    #pragma unroll
    for (int ot = 0; ot < 2; ++ot)
        #pragma unroll
        for (int r = 0; r < 4; ++r)
            bm[ot][r] = ws[512 + b*32 + ot*16 + kg*4 + r];

    // ---- T14 prefetch state: next 8 rows, 4 chunks/thread (main px only) ----
    float P[4][8];
    auto pf_issue = [&](int r0) {
        #pragma unroll
        for (int k = 0; k < 4; ++k) {
            int ci = tid + k*512;               // 8 rows * 4 g * 64 px = 2048
            int pm = ci & 63, t2 = ci >> 6;
            int g = t2 & 3, rr = t2 >> 2;
            load8(g, ystrip + r0 + rr, xstrip + pm, P[k]);
        }
    };
    auto pf_write = [&](int r0) {
        #pragma unroll
        for (int k = 0; k < 4; ++k) {
            int ci = tid + k*512;
            int pm = ci & 63, t2 = ci >> 6;
            int g = t2 & 3, rr = t2 >> 2;
            packwrite(r0 + rr, pm + 1, g, P[k]);
        }
    };
    auto halo_stage = [&](int r0) {             // 8 rows * 4 g * 2 = 64 chunks
        if (tid < 64) {
            int side = tid & 1, t2 = tid >> 1;
            int g = t2 & 3, rr = t2 >> 2;
            int p = side ? 65 : 0;
            float f[8];
            load8(g, ystrip + r0 + rr, xstrip + p - 1, f);
            packwrite(r0 + rr, p, g, f);
        }
    };

    pf_issue(9);                                // rows 9..16 for iter 1

    // prologue barrier: raw s_barrier — LDS writes visible, but prefetch
    // loads (register dests) stay in flight across it.
    asm volatile("s_waitcnt lgkmcnt(0)" ::: "memory");
    __builtin_amdgcn_s_barrier();
    asm volatile("" ::: "memory");

    for (int t = 0; t < 4; ++t) {
        const int orow = 8*t + w;               // this wave's output row
        const int gy   = ystrip + orow;

        float4v acc[4][2];
        #pragma unroll
        for (int c = 0; c < 4; ++c) {
            acc[c][0] = float4v{0.f, 0.f, 0.f, 0.f};
            acc[c][1] = float4v{0.f, 0.f, 0.f, 0.f};
        }

        #pragma unroll
        for (int dy = 0; dy < 3; ++dy) {
            // row orow+dy-1 lives in slot (orow+dy) % NSLOT  (slot(r)=(r+1)%NSLOT)
            const int rowbase = (int)((unsigned)(orow + dy) % NSLOT) * ROWS_;
            #pragma unroll
            for (int dx = 0; dx < 3; ++dx) {
                const int tap = dy*3 + dx;
                short8 a0 = *(const short8*)&wbuf[((tap*2 + 0)*64 + lane)*8];
                short8 a1 = *(const short8*)&wbuf[((tap*2 + 1)*64 + lane)*8];
                #pragma unroll
                for (int c = 0; c < 4; ++c) {
                    int p = c*16 + dx + ln15;               // LDS pixel index
                    int a = rowbase + p*PXS + ((kg ^ ((p >> 1) & 3)) * 8);
                    short8 xf = *(const short8*)&xbuf[a];
                    acc[c][0] = __builtin_amdgcn_mfma_f32_16x16x32_bf16(
                                    a0, xf, acc[c][0], 0, 0, 0);
                    acc[c][1] = __builtin_amdgcn_mfma_f32_16x16x32_bf16(
                                    a1, xf, acc[c][1], 0, 0, 0);
                }
            }
        }

        // post-compute barrier: all waves' window reads done.
        __syncthreads();

        // epilogue stores: D row(out) = kg*4 + r, col(pixel) = ln15
        #pragma unroll
        for (int c = 0; c < 4; ++c) {
            const int xcol = xstrip + c*16 + ln15;
            #pragma unroll
            for (int ot = 0; ot < 2; ++ot) {
                const int obase = ot*16 + kg*4;
                #pragma unroll
                for (int r = 0; r < 4; ++r) {
                    out[((size_t)(b*COUT + obase + r)*256 + gy)*256 + xcol] =
                        acc[c][ot][r] + bm[ot][r];
                }
            }
        }

        if (t < 3) {
            halo_stage(8*t + 9);        // wave 0 only: direct halo (64 chunks)
            pf_write(8*t + 9);          // pack+write prefetched 8 rows
            if (t < 2) pf_issue(8*t + 17);   // issue next tile's loads NOW
            // staging barrier: raw s_barrier + lgkmcnt(0) so the just-issued
            // prefetch loads are NOT drained (no vmcnt wait here).
            asm volatile("s_waitcnt lgkmcnt(0)" ::: "memory");
            __builtin_amdgcn_s_barrier();
            asm volatile("" ::: "memory");
        }
    }
}

extern "C" void kernel_launch(void* const* d_in, const int* in_sizes, int n_in,
                              void* d_out, int out_size, void* d_ws, size_t ws_size,
                              hipStream_t stream) {
    const float* x       = (const float*)d_in[0];
    const float* cond    = (const float*)d_in[1];
    const float* lpe     = (const float*)d_in[2];
    const float* weights = (const float*)d_in[3];
    const float* bias    = (const float*)d_in[4];
    const float* wa_w    = (const float*)d_in[5];
    const float* wa_b    = (const float*)d_in[6];
    const float* ba_w    = (const float*)d_in[7];
    const float* ba_b    = (const float*)d_in[8];
    float* outp = (float*)d_out;
    float* ws   = (float*)d_ws;    // 1024 floats: wadapt | bias*badapt

    adapt_kernel<<<dim3(B_), dim3(256), 0, stream>>>(
        cond, lpe, wa_w, wa_b, ba_w, ba_b, bias, ws);

    conv_kernel<<<dim3(W_/64, H_/32, B_), dim3(512), 0, stream>>>(
        x, weights, ws, outp);
}

// Round 7
// 300.616 us; speedup vs baseline: 1.0367x; 1.0367x over previous
//
#include <hip/hip_runtime.h>

// BatchAdaptiveConv2d via implicit GEMM on bf16 MFMA.
// out[b,o,y,x] = sum_{i,dy,dx} x[b,i,y+dy-1,x+dx-1] * W[i,o,dy,dx]*wadapt[b,i]
//               + bias[o]*badapt[b,o]
// R9 = R6/R7/R8 resubmitted (three consecutive GPUAcquisitionTimeouts).
// R6: VMEM-issue-rate fix. R2/R5 both ran at ~1.6-2.0 cyc/VMEM-instr (scalar
// dword loads across 256KB-strided channels) => ~2.7 TB/s cap regardless of
// occupancy. Now: float4 loads along x (1KB/wave-instr), register transpose
// 8ch x 4px -> bf16 granules -> ds_write_b128 into the UNCHANGED LDS layout.
// ~50x fewer VMEM instrs. Halo prefetched (no serial wave0 chain). No
// vmcnt(0) drains in the loop (post-MFMA barrier = lgkmcnt(0)+s_barrier).

#define B_    16
#define CIN   32
#define COUT  32
#define H_    256
#define W_    256
#define EMB2  512

#define XPX   66               // 64 + 2 halo pixels per LDS row
#define PXS   32               // ushorts per pixel (32 ch * bf16)
#define ROWS_ (XPX*PXS)        // 2112 ushorts per row-slot
#define NSLOT 10               // rolling window slots

using short8  = __attribute__((ext_vector_type(8))) short;
using float4v = __attribute__((ext_vector_type(4))) float;
using float4r = __attribute__((ext_vector_type(4))) float;

__device__ __forceinline__ unsigned short f2bf(float f) {
    unsigned u = __builtin_bit_cast(unsigned, f);
    u += 0x7FFFu + ((u >> 16) & 1u);      // RNE
    return (unsigned short)(u >> 16);
}
__device__ __forceinline__ unsigned pk2(float a, float b) {
    return (unsigned)f2bf(a) | ((unsigned)f2bf(b) << 16);
}

// ---------------- kernel 1: adapt coefficients ----------------
// ws[0..511] = wadapt[b][i]; ws[512..1023] = bias[o]*badapt[b][o]
__global__ __launch_bounds__(256) void adapt_kernel(
    const float* __restrict__ cond, const float* __restrict__ lpe,
    const float* __restrict__ wa_w, const float* __restrict__ wa_b,
    const float* __restrict__ ba_w, const float* __restrict__ ba_b,
    const float* __restrict__ bias, float* __restrict__ ws)
{
    __shared__ float iv[EMB2];
    __shared__ float partial[64][4];
    const int b = blockIdx.x;
    const int t = threadIdx.x;

    iv[t]       = cond[b*256 + t];
    iv[t + 256] = lpe[b*256 + t];
    __syncthreads();

    const int out  = t & 63;
    const int part = t >> 6;
    const float* row = (out < 32) ? (wa_w + out*EMB2) : (ba_w + (out-32)*EMB2);
    float s = 0.f;
    #pragma unroll 8
    for (int j = part*128; j < part*128 + 128; ++j) s += iv[j] * row[j];
    partial[out][part] = s;
    __syncthreads();

    if (t < 64) {
        float v = partial[t][0] + partial[t][1] + partial[t][2] + partial[t][3];
        if (t < 32) ws[b*32 + t] = v + wa_b[t];
        else {
            int o = t - 32;
            ws[512 + b*32 + o] = bias[o] * (v + ba_b[o]);
        }
    }
}

// ---------------- kernel 2: MFMA conv ----------------
// grid (W/64, H/32, B); block 512 = 8 waves. Wave w handles output row 8t+w.
__global__ __launch_bounds__(512, 4) void conv_kernel(
    const float* __restrict__ x, const float* __restrict__ weights,
    const float* __restrict__ ws, float* __restrict__ out)
{
    __shared__ __align__(16) unsigned short xbuf[NSLOT * ROWS_];   // 42240 B
    __shared__ __align__(16) unsigned short wbuf[9 * 2 * 64 * 8];  // 18432 B

    const int tid    = threadIdx.x;
    const int lane   = tid & 63;
    const int w      = tid >> 6;        // wave 0..7
    const int ln15   = lane & 15;
    const int kg     = lane >> 4;       // k-group 0..3
    const int xstrip = blockIdx.x * 64;
    const int ystrip = blockIdx.y * 32;
    const int b      = blockIdx.z;

    // ---- scaled weights -> wbuf[tap][ot][lane][j]: lane-consecutive 16B,
    //      conflict-free ds_read_b128 per (tap,ot).
    for (int idx = tid; idx < CIN*COUT*9; idx += 512) {
        int i   = idx / 288;
        int rem = idx - i*288;
        int o   = rem / 9;
        int tap = rem - o*9;
        float v = weights[idx] * ws[b*32 + i];
        wbuf[((tap*2 + (o>>4))*64 + ((i>>3)*16 + (o&15)))*8 + (i&7)] = f2bf(v);
    }

    // ---- helpers ----
    // main-px vector load: 8 channels x 4 consecutive px (8x dwordx4)
    auto ld_main = [&](int gy, int g, int q, float4r (&L)[8]) {
        if ((unsigned)gy < 256u) {
            const float* src = x + (((size_t)(b*CIN + g*8) << 16) + (gy << 8)
                                    + (xstrip + 4*q));
            #pragma unroll
            for (int j = 0; j < 8; ++j)
                L[j] = *(const float4r*)&src[(size_t)j << 16];
        } else {
            #pragma unroll
            for (int j = 0; j < 8; ++j) L[j] = float4r{0.f, 0.f, 0.f, 0.f};
        }
    };
    // register transpose (8ch x 4px -> 4 granules) + swizzled b128 writes.
    // k-stagger (n+q)&3 spreads write banks (16-way -> ~8-way).
    auto wr_main = [&](int r, int g, int q, const float4r (&L)[8]) {
        unsigned slot = (unsigned)(r + 1) % NSLOT;
        #pragma unroll
        for (int n = 0; n < 4; ++n) {
            int k = (n + q) & 3;
            int p = 4*q + k + 1;                 // LDS pixel index 1..64
            uint4 pk;
            pk.x = pk2(L[0][k], L[1][k]);
            pk.y = pk2(L[2][k], L[3][k]);
            pk.z = pk2(L[4][k], L[5][k]);
            pk.w = pk2(L[6][k], L[7][k]);
            *(uint4*)&xbuf[slot*ROWS_ + p*PXS + ((g ^ ((p >> 1) & 3)) * 8)] = pk;
        }
    };
    // halo: one px, 8 channels, scalar loads (rare: 64 granules/iter)
    auto load8 = [&](int g, int yy, int xx, float (&f)[8]) {
        if (((unsigned)yy < 256u) & ((unsigned)xx < 256u)) {
            const float* src = x + (((size_t)(b*CIN + g*8) << 16) + (yy << 8) + xx);
            #pragma unroll
            for (int j = 0; j < 8; ++j) f[j] = src[(size_t)j << 16];
        } else {
            #pragma unroll
            for (int j = 0; j < 8; ++j) f[j] = 0.f;
        }
    };
    auto packwrite = [&](int r, int p, int g, const float (&f)[8]) {
        unsigned slot = (unsigned)(r + 1) % NSLOT;
        unsigned dst  = slot*ROWS_ + p*PXS + ((g ^ ((p >> 1) & 3)) * 8);
        uint4 pk;
        pk.x = pk2(f[0], f[1]); pk.y = pk2(f[2], f[3]);
        pk.z = pk2(f[4], f[5]); pk.w = pk2(f[6], f[7]);
        *(uint4*)&xbuf[dst] = pk;
    };

    // ---- prologue: direct-stage rows -1..8 (10 rows) ----
    // main: 10 rows * 4 g * 16 quads = 640 chunks
    #pragma unroll
    for (int k2 = 0; k2 < 2; ++k2) {
        int ci = tid + k2*512;
        if (ci < 640) {
            int q = ci & 15, g = (ci >> 4) & 3, rr = ci >> 6;   // rr 0..9
            float4r L[8];
            ld_main(ystrip + rr - 1, g, q, L);
            wr_main(rr - 1, g, q, L);
        }
    }
    // halo: 10 rows * 4 g * 2 sides = 80 granules
    if (tid < 80) {
        int s = tid & 1, g = (tid >> 1) & 3, rr = tid >> 3;     // rr 0..9
        int p = s ? 65 : 0;
        float f[8];
        load8(g, ystrip + rr - 1, xstrip + p - 1, f);
        packwrite(rr - 1, p, g, f);
    }

    // ---- per-lane modulated bias (out = ot*16 + kg*4 + r) ----
    float bm[2][4];
    #pragma unroll
    for (int ot = 0; ot < 2; ++ot)
        #pragma unroll
        for (int r = 0; r < 4; ++r)
            bm[ot][r] = ws[512 + b*32 + ot*16 + kg*4 + r];

    // ---- T14 prefetch state: next 8 rows ----
    float4r PM[8];                 // main: 8 ch x 4 px (this thread's chunk)
    float   PH[8];                 // halo: 8 ch x 1 px (wave 0 only)
    auto pf_issue = [&](int r0) {
        int q = tid & 15, g = (tid >> 4) & 3, rr = tid >> 6;    // rr 0..7
        ld_main(ystrip + r0 + rr, g, q, PM);
        if (tid < 64) {
            int s = tid & 1, hg = (tid >> 1) & 3, hr = tid >> 3;
            int p = s ? 65 : 0;
            load8(hg, ystrip + r0 + hr, xstrip + p - 1, PH);
        }
    };
    auto pf_write = [&](int r0) {
        int q = tid & 15, g = (tid >> 4) & 3, rr = tid >> 6;
        wr_main(r0 + rr, g, q, PM);
        if (tid < 64) {
            int s = tid & 1, hg = (tid >> 1) & 3, hr = tid >> 3;
            int p = s ? 65 : 0;
            packwrite(r0 + hr, p, hg, PH);
        }
    };

    pf_issue(9);                                // rows 9..16 for iter 1

    // prologue barrier: LDS writes visible; prefetch loads stay in flight.
    asm volatile("s_waitcnt lgkmcnt(0)" ::: "memory");
    __builtin_amdgcn_s_barrier();
    asm volatile("" ::: "memory");

    for (int t = 0; t < 4; ++t) {
        const int orow = 8*t + w;               // this wave's output row
        const int gy   = ystrip + orow;

        float4v acc[4][2];
        #pragma unroll
        for (int c = 0; c < 4; ++c) {
            acc[c][0] = float4v{0.f, 0.f, 0.f, 0.f};
            acc[c][1] = float4v{0.f, 0.f, 0.f, 0.f};
        }

        #pragma unroll
        for (int dy = 0; dy < 3; ++dy) {
            // row orow+dy-1 lives in slot (orow+dy) % NSLOT
            const int rowbase = (int)((unsigned)(orow + dy) % NSLOT) * ROWS_;
            #pragma unroll
            for (int dx = 0; dx < 3; ++dx) {
                const int tap = dy*3 + dx;
                short8 a0 = *(const short8*)&wbuf[((tap*2 + 0)*64 + lane)*8];
                short8 a1 = *(const short8*)&wbuf[((tap*2 + 1)*64 + lane)*8];
                #pragma unroll
                for (int c = 0; c < 4; ++c) {
                    int p = c*16 + dx + ln15;               // LDS pixel index
                    int a = rowbase + p*PXS + ((kg ^ ((p >> 1) & 3)) * 8);
                    short8 xf = *(const short8*)&xbuf[a];
                    acc[c][0] = __builtin_amdgcn_mfma_f32_16x16x32_bf16(
                                    a0, xf, acc[c][0], 0, 0, 0);
                    acc[c][1] = __builtin_amdgcn_mfma_f32_16x16x32_bf16(
                                    a1, xf, acc[c][1], 0, 0, 0);
                }
            }
        }

        // post-compute barrier: NO vmcnt drain — only LDS reads must be done
        // before pf_write overwrites slots. Prefetch loads stay in flight.
        asm volatile("s_waitcnt lgkmcnt(0)" ::: "memory");
        __builtin_amdgcn_s_barrier();
        asm volatile("" ::: "memory");

        // epilogue stores: D row(out) = kg*4 + r, col(pixel) = ln15
        #pragma unroll
        for (int c = 0; c < 4; ++c) {
            const int xcol = xstrip + c*16 + ln15;
            #pragma unroll
            for (int ot = 0; ot < 2; ++ot) {
                const int obase = ot*16 + kg*4;
                #pragma unroll
                for (int r = 0; r < 4; ++r) {
                    out[((size_t)(b*COUT + obase + r)*256 + gy)*256 + xcol] =
                        acc[c][ot][r] + bm[ot][r];
                }
            }
        }

        if (t < 3) {
            pf_write(8*t + 9);          // compiler-precise vmcnt on PM/PH only
            if (t < 2) pf_issue(8*t + 17);   // issue next batch NOW
            // staging barrier: ds_writes visible; new loads NOT drained.
            asm volatile("s_waitcnt lgkmcnt(0)" ::: "memory");
            __builtin_amdgcn_s_barrier();
            asm volatile("" ::: "memory");
        }
    }
}

extern "C" void kernel_launch(void* const* d_in, const int* in_sizes, int n_in,
                              void* d_out, int out_size, void* d_ws, size_t ws_size,
                              hipStream_t stream) {
    const float* x       = (const float*)d_in[0];
    const float* cond    = (const float*)d_in[1];
    const float* lpe     = (const float*)d_in[2];
    const float* weights = (const float*)d_in[3];
    const float* bias    = (const float*)d_in[4];
    const float* wa_w    = (const float*)d_in[5];
    const float* wa_b    = (const float*)d_in[6];
    const float* ba_w    = (const float*)d_in[7];
    const float* ba_b    = (const float*)d_in[8];
    float* outp = (float*)d_out;
    float* ws   = (float*)d_ws;    // 1024 floats: wadapt | bias*badapt

    adapt_kernel<<<dim3(B_), dim3(256), 0, stream>>>(
        cond, lpe, wa_w, wa_b, ba_w, ba_b, bias, ws);

    conv_kernel<<<dim3(W_/64, H_/32, B_), dim3(512), 0, stream>>>(
        x, weights, ws, outp);
}

// Round 8
// 296.248 us; speedup vs baseline: 1.0520x; 1.0147x over previous
//
#include <hip/hip_runtime.h>

// BatchAdaptiveConv2d via implicit GEMM on bf16 MFMA.
// out[b,o,y,x] = sum_{i,dy,dx} x[b,i,y+dy-1,x+dx-1] * W[i,o,dy,dx]*wadapt[b,i]
//               + bias[o]*badapt[b,o]
// R10 = R2 geometry + R9 machinery.
//  Counter-backed diagnosis: R9's 8-wave blocks inflated HBM traffic 253->347MB
//  (quarter-line stores -> L2 partial-line eviction RMW at 4MB/XCD dirty set);
//  R2's 4-wave blocks showed WRITE==ideal. R9's vectorized staging raised BW
//  2.64->3.10 TB/s. Combine: 256-thread blocks, NSLOT=8, 4-row steps (R2's
//  proven slot schedule) + dwordx4 loads / reg transpose / b128 LDS writes /
//  reg-prefetch pipeline (R9's proven staging). 52224B LDS -> 3 blocks/CU.

#define B_    16
#define CIN   32
#define COUT  32
#define H_    256
#define W_    256
#define EMB2  512

#define XPX   66               // 64 + 2 halo pixels per LDS row
#define PXS   32               // ushorts per pixel (32 ch * bf16)
#define ROWS_ (XPX*PXS)        // 2112 ushorts per row-slot
#define NSLOT 8                // rolling window slots (R2-proven)

using short8  = __attribute__((ext_vector_type(8))) short;
using float4v = __attribute__((ext_vector_type(4))) float;
using float4r = __attribute__((ext_vector_type(4))) float;

__device__ __forceinline__ unsigned short f2bf(float f) {
    unsigned u = __builtin_bit_cast(unsigned, f);
    u += 0x7FFFu + ((u >> 16) & 1u);      // RNE
    return (unsigned short)(u >> 16);
}
__device__ __forceinline__ unsigned pk2(float a, float b) {
    return (unsigned)f2bf(a) | ((unsigned)f2bf(b) << 16);
}

// ---------------- kernel 1: adapt coefficients ----------------
// ws[0..511] = wadapt[b][i]; ws[512..1023] = bias[o]*badapt[b][o]
__global__ __launch_bounds__(256) void adapt_kernel(
    const float* __restrict__ cond, const float* __restrict__ lpe,
    const float* __restrict__ wa_w, const float* __restrict__ wa_b,
    const float* __restrict__ ba_w, const float* __restrict__ ba_b,
    const float* __restrict__ bias, float* __restrict__ ws)
{
    __shared__ float iv[EMB2];
    __shared__ float partial[64][4];
    const int b = blockIdx.x;
    const int t = threadIdx.x;

    iv[t]       = cond[b*256 + t];
    iv[t + 256] = lpe[b*256 + t];
    __syncthreads();

    const int out  = t & 63;
    const int part = t >> 6;
    const float* row = (out < 32) ? (wa_w + out*EMB2) : (ba_w + (out-32)*EMB2);
    float s = 0.f;
    #pragma unroll 8
    for (int j = part*128; j < part*128 + 128; ++j) s += iv[j] * row[j];
    partial[out][part] = s;
    __syncthreads();

    if (t < 64) {
        float v = partial[t][0] + partial[t][1] + partial[t][2] + partial[t][3];
        if (t < 32) ws[b*32 + t] = v + wa_b[t];
        else {
            int o = t - 32;
            ws[512 + b*32 + o] = bias[o] * (v + ba_b[o]);
        }
    }
}

// ---------------- kernel 2: MFMA conv ----------------
// grid (W/64, H/32, B); block 256 = 4 waves. Wave w handles output row 4t+w.
__global__ __launch_bounds__(256, 3) void conv_kernel(
    const float* __restrict__ x, const float* __restrict__ weights,
    const float* __restrict__ ws, float* __restrict__ out)
{
    __shared__ __align__(16) unsigned short xbuf[NSLOT * ROWS_];   // 33792 B
    __shared__ __align__(16) unsigned short wbuf[9 * 2 * 64 * 8];  // 18432 B

    const int tid    = threadIdx.x;
    const int lane   = tid & 63;
    const int w      = tid >> 6;        // wave 0..3
    const int ln15   = lane & 15;
    const int kg     = lane >> 4;       // k-group 0..3
    const int xstrip = blockIdx.x * 64;
    const int ystrip = blockIdx.y * 32;
    const int b      = blockIdx.z;

    // ---- scaled weights -> wbuf[tap][ot][lane][j]: lane-consecutive 16B,
    //      conflict-free ds_read_b128 per (tap,ot).
    for (int idx = tid; idx < CIN*COUT*9; idx += 256) {
        int i   = idx / 288;
        int rem = idx - i*288;
        int o   = rem / 9;
        int tap = rem - o*9;
        float v = weights[idx] * ws[b*32 + i];
        wbuf[((tap*2 + (o>>4))*64 + ((i>>3)*16 + (o&15)))*8 + (i&7)] = f2bf(v);
    }

    // ---- helpers ----
    // main-px vector load: 8 channels x 4 consecutive px (8x dwordx4)
    auto ld_main = [&](int gy, int g, int q, float4r (&L)[8]) {
        if ((unsigned)gy < 256u) {
            const float* src = x + (((size_t)(b*CIN + g*8) << 16) + (gy << 8)
                                    + (xstrip + 4*q));
            #pragma unroll
            for (int j = 0; j < 8; ++j)
                L[j] = *(const float4r*)&src[(size_t)j << 16];
        } else {
            #pragma unroll
            for (int j = 0; j < 8; ++j) L[j] = float4r{0.f, 0.f, 0.f, 0.f};
        }
    };
    // register transpose (8ch x 4px -> 4 granules) + swizzled b128 writes.
    // k-stagger (n+q)&3 spreads write banks.
    auto wr_main = [&](int r, int g, int q, const float4r (&L)[8]) {
        unsigned slot = (unsigned)(r + 1) & 7;
        #pragma unroll
        for (int n = 0; n < 4; ++n) {
            int k = (n + q) & 3;
            int p = 4*q + k + 1;                 // LDS pixel index 1..64
            uint4 pk;
            pk.x = pk2(L[0][k], L[1][k]);
            pk.y = pk2(L[2][k], L[3][k]);
            pk.z = pk2(L[4][k], L[5][k]);
            pk.w = pk2(L[6][k], L[7][k]);
            *(uint4*)&xbuf[slot*ROWS_ + p*PXS + ((g ^ ((p >> 1) & 3)) * 8)] = pk;
        }
    };
    // halo: one px, 8 channels, scalar loads (rare)
    auto load8 = [&](int g, int yy, int xx, float (&f)[8]) {
        if (((unsigned)yy < 256u) & ((unsigned)xx < 256u)) {
            const float* src = x + (((size_t)(b*CIN + g*8) << 16) + (yy << 8) + xx);
            #pragma unroll
            for (int j = 0; j < 8; ++j) f[j] = src[(size_t)j << 16];
        } else {
            #pragma unroll
            for (int j = 0; j < 8; ++j) f[j] = 0.f;
        }
    };
    auto packwrite = [&](int r, int p, int g, const float (&f)[8]) {
        unsigned slot = (unsigned)(r + 1) & 7;
        unsigned dst  = slot*ROWS_ + p*PXS + ((g ^ ((p >> 1) & 3)) * 8);
        uint4 pk;
        pk.x = pk2(f[0], f[1]); pk.y = pk2(f[2], f[3]);
        pk.z = pk2(f[4], f[5]); pk.w = pk2(f[6], f[7]);
        *(uint4*)&xbuf[dst] = pk;
    };

    // ---- prologue: direct-stage rows -1..4 (6 rows, slots 0..5) ----
    // main: 6 rows * 4 g * 16 quads = 384 chunks
    #pragma unroll
    for (int k2 = 0; k2 < 2; ++k2) {
        int ci = tid + k2*256;
        if (ci < 384) {
            int q = ci & 15, g = (ci >> 4) & 3, rr = ci >> 6;   // rr 0..5
            float4r L[8];
            ld_main(ystrip + rr - 1, g, q, L);
            wr_main(rr - 1, g, q, L);
        }
    }
    // halo: 6 rows * 4 g * 2 sides = 48 granules
    if (tid < 48) {
        int s = tid & 1, g = (tid >> 1) & 3, rr = tid >> 3;     // rr 0..5
        int p = s ? 65 : 0;
        float f[8];
        load8(g, ystrip + rr - 1, xstrip + p - 1, f);
        packwrite(rr - 1, p, g, f);
    }

    // ---- per-lane modulated bias (out = ot*16 + kg*4 + r) ----
    float bm[2][4];
    #pragma unroll
    for (int ot = 0; ot < 2; ++ot)
        #pragma unroll
        for (int r = 0; r < 4; ++r)
            bm[ot][r] = ws[512 + b*32 + ot*16 + kg*4 + r];

    // ---- T14 prefetch state: next 4 rows, exactly 1 chunk/thread ----
    float4r PM[8];                 // main: 8 ch x 4 px
    float   PH[8];                 // halo: 8 ch x 1 px (tid<32 only)
    auto pf_issue = [&](int r0) {
        int q = tid & 15, g = (tid >> 4) & 3, rr = tid >> 6;    // rr 0..3
        ld_main(ystrip + r0 + rr, g, q, PM);
        if (tid < 32) {
            int s = tid & 1, hg = (tid >> 1) & 3, hr = tid >> 3; // hr 0..3
            int p = s ? 65 : 0;
            load8(hg, ystrip + r0 + hr, xstrip + p - 1, PH);
        }
    };
    auto pf_write = [&](int r0) {
        int q = tid & 15, g = (tid >> 4) & 3, rr = tid >> 6;
        wr_main(r0 + rr, g, q, PM);
        if (tid < 32) {
            int s = tid & 1, hg = (tid >> 1) & 3, hr = tid >> 3;
            int p = s ? 65 : 0;
            packwrite(r0 + hr, p, hg, PH);
        }
    };

    pf_issue(5);                                // rows 5..8 for iter 1

    // prologue barrier: LDS writes visible; prefetch loads stay in flight.
    asm volatile("s_waitcnt lgkmcnt(0)" ::: "memory");
    __builtin_amdgcn_s_barrier();
    asm volatile("" ::: "memory");

    for (int t = 0; t < 8; ++t) {
        const int orow = 4*t + w;               // this wave's output row
        const int gy   = ystrip + orow;

        float4v acc[4][2];
        #pragma unroll
        for (int c = 0; c < 4; ++c) {
            acc[c][0] = float4v{0.f, 0.f, 0.f, 0.f};
            acc[c][1] = float4v{0.f, 0.f, 0.f, 0.f};
        }

        #pragma unroll
        for (int dy = 0; dy < 3; ++dy) {
            // row orow+dy-1 lives in slot (orow+dy) & 7  (slot(r)=(r+1)&7)
            const int rowbase = ((orow + dy) & 7) * ROWS_;
            #pragma unroll
            for (int dx = 0; dx < 3; ++dx) {
                const int tap = dy*3 + dx;
                short8 a0 = *(const short8*)&wbuf[((tap*2 + 0)*64 + lane)*8];
                short8 a1 = *(const short8*)&wbuf[((tap*2 + 1)*64 + lane)*8];
                #pragma unroll
                for (int c = 0; c < 4; ++c) {
                    int p = c*16 + dx + ln15;               // LDS pixel index
                    int a = rowbase + p*PXS + ((kg ^ ((p >> 1) & 3)) * 8);
                    short8 xf = *(const short8*)&xbuf[a];
                    acc[c][0] = __builtin_amdgcn_mfma_f32_16x16x32_bf16(
                                    a0, xf, acc[c][0], 0, 0, 0);
                    acc[c][1] = __builtin_amdgcn_mfma_f32_16x16x32_bf16(
                                    a1, xf, acc[c][1], 0, 0, 0);
                }
            }
        }

        // post-compute barrier: NO vmcnt drain — only LDS reads must be done
        // before pf_write overwrites slots. Prefetch loads stay in flight.
        asm volatile("s_waitcnt lgkmcnt(0)" ::: "memory");
        __builtin_amdgcn_s_barrier();
        asm volatile("" ::: "memory");

        // epilogue stores: D row(out) = kg*4 + r, col(pixel) = ln15
        #pragma unroll
        for (int c = 0; c < 4; ++c) {
            const int xcol = xstrip + c*16 + ln15;
            #pragma unroll
            for (int ot = 0; ot < 2; ++ot) {
                const int obase = ot*16 + kg*4;
                #pragma unroll
                for (int r = 0; r < 4; ++r) {
                    out[((size_t)(b*COUT + obase + r)*256 + gy)*256 + xcol] =
                        acc[c][ot][r] + bm[ot][r];
                }
            }
        }

        if (t < 7) {
            pf_write(4*t + 5);          // compiler-precise vmcnt on PM/PH only
            if (t < 6) pf_issue(4*t + 9);    // issue next batch NOW
            // staging barrier: ds_writes visible; new loads NOT drained.
            asm volatile("s_waitcnt lgkmcnt(0)" ::: "memory");
            __builtin_amdgcn_s_barrier();
            asm volatile("" ::: "memory");
        }
    }
}

extern "C" void kernel_launch(void* const* d_in, const int* in_sizes, int n_in,
                              void* d_out, int out_size, void* d_ws, size_t ws_size,
                              hipStream_t stream) {
    const float* x       = (const float*)d_in[0];
    const float* cond    = (const float*)d_in[1];
    const float* lpe     = (const float*)d_in[2];
    const float* weights = (const float*)d_in[3];
    const float* bias    = (const float*)d_in[4];
    const float* wa_w    = (const float*)d_in[5];
    const float* wa_b    = (const float*)d_in[6];
    const float* ba_w    = (const float*)d_in[7];
    const float* ba_b    = (const float*)d_in[8];
    float* outp = (float*)d_out;
    float* ws   = (float*)d_ws;    // 1024 floats: wadapt | bias*badapt

    adapt_kernel<<<dim3(B_), dim3(256), 0, stream>>>(
        cond, lpe, wa_w, wa_b, ba_w, ba_b, bias, ws);

    conv_kernel<<<dim3(W_/64, H_/32, B_), dim3(256), 0, stream>>>(
        x, weights, ws, outp);
}

// Round 9
// 285.621 us; speedup vs baseline: 1.0911x; 1.0372x over previous
//
#include <hip/hip_runtime.h>

// BatchAdaptiveConv2d via implicit GEMM on bf16 MFMA.
// out[b,o,y,x] = sum_{i,dy,dx} x[b,i,y+dy-1,x+dx-1] * W[i,o,dy,dx]*wadapt[b,i]
//               + bias[o]*badapt[b,o]
// R11 = R10 with ONE change: store/prefetch ISSUE-ORDER swap.
//  Diagnosis (R2/R5/R9/R10 all fit dur = bytes / ~2.7 TB/s; T_iter = 30k cyc
//  vs ~2.5k cyc of work): vmcnt retires IN ISSUE ORDER, and each iteration's
//  pf_write vmcnt-wait sat behind the PREVIOUS iteration's 32 global stores
//  (issued between the prefetch loads and their consumer). Store-commit
//  latency under chip-wide write pressure ended up on every iteration's
//  critical path (R2's __syncthreads vmcnt(0) drain: same poison, explicit).
//  Fix: issue [pf_write; pf_issue] BEFORE the stores, fence, then stores.
//  Loads are now older than all nearby stores -> pf_write's wait completes on
//  load-return (~900cyc, hidden under MFMA); stores drain fully async.

#define B_    16
#define CIN   32
#define COUT  32
#define H_    256
#define W_    256
#define EMB2  512

#define XPX   66               // 64 + 2 halo pixels per LDS row
#define PXS   32               // ushorts per pixel (32 ch * bf16)
#define ROWS_ (XPX*PXS)        // 2112 ushorts per row-slot
#define NSLOT 8                // rolling window slots

using short8  = __attribute__((ext_vector_type(8))) short;
using float4v = __attribute__((ext_vector_type(4))) float;
using float4r = __attribute__((ext_vector_type(4))) float;

__device__ __forceinline__ unsigned short f2bf(float f) {
    unsigned u = __builtin_bit_cast(unsigned, f);
    u += 0x7FFFu + ((u >> 16) & 1u);      // RNE
    return (unsigned short)(u >> 16);
}
__device__ __forceinline__ unsigned pk2(float a, float b) {
    return (unsigned)f2bf(a) | ((unsigned)f2bf(b) << 16);
}

// ---------------- kernel 1: adapt coefficients ----------------
// ws[0..511] = wadapt[b][i]; ws[512..1023] = bias[o]*badapt[b][o]
__global__ __launch_bounds__(256) void adapt_kernel(
    const float* __restrict__ cond, const float* __restrict__ lpe,
    const float* __restrict__ wa_w, const float* __restrict__ wa_b,
    const float* __restrict__ ba_w, const float* __restrict__ ba_b,
    const float* __restrict__ bias, float* __restrict__ ws)
{
    __shared__ float iv[EMB2];
    __shared__ float partial[64][4];
    const int b = blockIdx.x;
    const int t = threadIdx.x;

    iv[t]       = cond[b*256 + t];
    iv[t + 256] = lpe[b*256 + t];
    __syncthreads();

    const int out  = t & 63;
    const int part = t >> 6;
    const float* row = (out < 32) ? (wa_w + out*EMB2) : (ba_w + (out-32)*EMB2);
    float s = 0.f;
    #pragma unroll 8
    for (int j = part*128; j < part*128 + 128; ++j) s += iv[j] * row[j];
    partial[out][part] = s;
    __syncthreads();

    if (t < 64) {
        float v = partial[t][0] + partial[t][1] + partial[t][2] + partial[t][3];
        if (t < 32) ws[b*32 + t] = v + wa_b[t];
        else {
            int o = t - 32;
            ws[512 + b*32 + o] = bias[o] * (v + ba_b[o]);
        }
    }
}

// ---------------- kernel 2: MFMA conv ----------------
// grid (W/64, H/32, B); block 256 = 4 waves. Wave w handles output row 4t+w.
__global__ __launch_bounds__(256, 3) void conv_kernel(
    const float* __restrict__ x, const float* __restrict__ weights,
    const float* __restrict__ ws, float* __restrict__ out)
{
    __shared__ __align__(16) unsigned short xbuf[NSLOT * ROWS_];   // 33792 B
    __shared__ __align__(16) unsigned short wbuf[9 * 2 * 64 * 8];  // 18432 B

    const int tid    = threadIdx.x;
    const int lane   = tid & 63;
    const int w      = tid >> 6;        // wave 0..3
    const int ln15   = lane & 15;
    const int kg     = lane >> 4;       // k-group 0..3
    const int xstrip = blockIdx.x * 64;
    const int ystrip = blockIdx.y * 32;
    const int b      = blockIdx.z;

    // ---- scaled weights -> wbuf[tap][ot][lane][j]: lane-consecutive 16B,
    //      conflict-free ds_read_b128 per (tap,ot).
    for (int idx = tid; idx < CIN*COUT*9; idx += 256) {
        int i   = idx / 288;
        int rem = idx - i*288;
        int o   = rem / 9;
        int tap = rem - o*9;
        float v = weights[idx] * ws[b*32 + i];
        wbuf[((tap*2 + (o>>4))*64 + ((i>>3)*16 + (o&15)))*8 + (i&7)] = f2bf(v);
    }

    // ---- helpers ----
    // main-px vector load: 8 channels x 4 consecutive px (8x dwordx4)
    auto ld_main = [&](int gy, int g, int q, float4r (&L)[8]) {
        if ((unsigned)gy < 256u) {
            const float* src = x + (((size_t)(b*CIN + g*8) << 16) + (gy << 8)
                                    + (xstrip + 4*q));
            #pragma unroll
            for (int j = 0; j < 8; ++j)
                L[j] = *(const float4r*)&src[(size_t)j << 16];
        } else {
            #pragma unroll
            for (int j = 0; j < 8; ++j) L[j] = float4r{0.f, 0.f, 0.f, 0.f};
        }
    };
    // register transpose (8ch x 4px -> 4 granules) + swizzled b128 writes.
    // k-stagger (n+q)&3 spreads write banks.
    auto wr_main = [&](int r, int g, int q, const float4r (&L)[8]) {
        unsigned slot = (unsigned)(r + 1) & 7;
        #pragma unroll
        for (int n = 0; n < 4; ++n) {
            int k = (n + q) & 3;
            int p = 4*q + k + 1;                 // LDS pixel index 1..64
            uint4 pk;
            pk.x = pk2(L[0][k], L[1][k]);
            pk.y = pk2(L[2][k], L[3][k]);
            pk.z = pk2(L[4][k], L[5][k]);
            pk.w = pk2(L[6][k], L[7][k]);
            *(uint4*)&xbuf[slot*ROWS_ + p*PXS + ((g ^ ((p >> 1) & 3)) * 8)] = pk;
        }
    };
    // halo: one px, 8 channels, scalar loads (rare)
    auto load8 = [&](int g, int yy, int xx, float (&f)[8]) {
        if (((unsigned)yy < 256u) & ((unsigned)xx < 256u)) {
            const float* src = x + (((size_t)(b*CIN + g*8) << 16) + (yy << 8) + xx);
            #pragma unroll
            for (int j = 0; j < 8; ++j) f[j] = src[(size_t)j << 16];
        } else {
            #pragma unroll
            for (int j = 0; j < 8; ++j) f[j] = 0.f;
        }
    };
    auto packwrite = [&](int r, int p, int g, const float (&f)[8]) {
        unsigned slot = (unsigned)(r + 1) & 7;
        unsigned dst  = slot*ROWS_ + p*PXS + ((g ^ ((p >> 1) & 3)) * 8);
        uint4 pk;
        pk.x = pk2(f[0], f[1]); pk.y = pk2(f[2], f[3]);
        pk.z = pk2(f[4], f[5]); pk.w = pk2(f[6], f[7]);
        *(uint4*)&xbuf[dst] = pk;
    };

    // ---- prologue: direct-stage rows -1..4 (6 rows, slots 0..5) ----
    // main: 6 rows * 4 g * 16 quads = 384 chunks
    #pragma unroll
    for (int k2 = 0; k2 < 2; ++k2) {
        int ci = tid + k2*256;
        if (ci < 384) {
            int q = ci & 15, g = (ci >> 4) & 3, rr = ci >> 6;   // rr 0..5
            float4r L[8];
            ld_main(ystrip + rr - 1, g, q, L);
            wr_main(rr - 1, g, q, L);
        }
    }
    // halo: 6 rows * 4 g * 2 sides = 48 granules
    if (tid < 48) {
        int s = tid & 1, g = (tid >> 1) & 3, rr = tid >> 3;     // rr 0..5
        int p = s ? 65 : 0;
        float f[8];
        load8(g, ystrip + rr - 1, xstrip + p - 1, f);
        packwrite(rr - 1, p, g, f);
    }

    // ---- per-lane modulated bias (out = ot*16 + kg*4 + r) ----
    float bm[2][4];
    #pragma unroll
    for (int ot = 0; ot < 2; ++ot)
        #pragma unroll
        for (int r = 0; r < 4; ++r)
            bm[ot][r] = ws[512 + b*32 + ot*16 + kg*4 + r];

    // ---- T14 prefetch state: next 4 rows, exactly 1 chunk/thread ----
    float4r PM[8];                 // main: 8 ch x 4 px
    float   PH[8];                 // halo: 8 ch x 1 px (tid<32 only)
    auto pf_issue = [&](int r0) {
        int q = tid & 15, g = (tid >> 4) & 3, rr = tid >> 6;    // rr 0..3
        ld_main(ystrip + r0 + rr, g, q, PM);
        if (tid < 32) {
            int s = tid & 1, hg = (tid >> 1) & 3, hr = tid >> 3; // hr 0..3
            int p = s ? 65 : 0;
            load8(hg, ystrip + r0 + hr, xstrip + p - 1, PH);
        }
    };
    auto pf_write = [&](int r0) {
        int q = tid & 15, g = (tid >> 4) & 3, rr = tid >> 6;
        wr_main(r0 + rr, g, q, PM);
        if (tid < 32) {
            int s = tid & 1, hg = (tid >> 1) & 3, hr = tid >> 3;
            int p = s ? 65 : 0;
            packwrite(r0 + hr, p, hg, PH);
        }
    };

    pf_issue(5);                                // rows 5..8 for iter 1

    // prologue barrier: LDS writes visible; prefetch loads stay in flight.
    asm volatile("s_waitcnt lgkmcnt(0)" ::: "memory");
    __builtin_amdgcn_s_barrier();
    asm volatile("" ::: "memory");

    for (int t = 0; t < 8; ++t) {
        const int orow = 4*t + w;               // this wave's output row
        const int gy   = ystrip + orow;

        float4v acc[4][2];
        #pragma unroll
        for (int c = 0; c < 4; ++c) {
            acc[c][0] = float4v{0.f, 0.f, 0.f, 0.f};
            acc[c][1] = float4v{0.f, 0.f, 0.f, 0.f};
        }

        #pragma unroll
        for (int dy = 0; dy < 3; ++dy) {
            // row orow+dy-1 lives in slot (orow+dy) & 7  (slot(r)=(r+1)&7)
            const int rowbase = ((orow + dy) & 7) * ROWS_;
            #pragma unroll
            for (int dx = 0; dx < 3; ++dx) {
                const int tap = dy*3 + dx;
                short8 a0 = *(const short8*)&wbuf[((tap*2 + 0)*64 + lane)*8];
                short8 a1 = *(const short8*)&wbuf[((tap*2 + 1)*64 + lane)*8];
                #pragma unroll
                for (int c = 0; c < 4; ++c) {
                    int p = c*16 + dx + ln15;               // LDS pixel index
                    int a = rowbase + p*PXS + ((kg ^ ((p >> 1) & 3)) * 8);
                    short8 xf = *(const short8*)&xbuf[a];
                    acc[c][0] = __builtin_amdgcn_mfma_f32_16x16x32_bf16(
                                    a0, xf, acc[c][0], 0, 0, 0);
                    acc[c][1] = __builtin_amdgcn_mfma_f32_16x16x32_bf16(
                                    a1, xf, acc[c][1], 0, 0, 0);
                }
            }
        }

        // post-compute barrier: all waves' LDS window reads done.
        asm volatile("s_waitcnt lgkmcnt(0)" ::: "memory");
        __builtin_amdgcn_s_barrier();
        asm volatile("" ::: "memory");

        // ---- prefetch FIRST: pf_write waits vmcnt on PM/PH loads that are
        // OLDER than any un-retired stores only from 2 iterations back (long
        // gone). pf_issue's new loads become OLDER than this iter's stores,
        // so next iter's wait never sits behind store commit. ----
        if (t < 7) {
            pf_write(4*t + 5);
            if (t < 6) pf_issue(4*t + 9);
        }

        // compiler fence: keep the stores BELOW the prefetch loads.
        asm volatile("" ::: "memory");

        // epilogue stores: D row(out) = kg*4 + r, col(pixel) = ln15
        // Issued last; nothing in the loop ever waits on their completion.
        #pragma unroll
        for (int c = 0; c < 4; ++c) {
            const int xcol = xstrip + c*16 + ln15;
            #pragma unroll
            for (int ot = 0; ot < 2; ++ot) {
                const int obase = ot*16 + kg*4;
                #pragma unroll
                for (int r = 0; r < 4; ++r) {
                    out[((size_t)(b*COUT + obase + r)*256 + gy)*256 + xcol] =
                        acc[c][ot][r] + bm[ot][r];
                }
            }
        }

        if (t < 7) {
            // staging barrier: ds_writes visible; stores/loads NOT drained.
            asm volatile("s_waitcnt lgkmcnt(0)" ::: "memory");
            __builtin_amdgcn_s_barrier();
            asm volatile("" ::: "memory");
        }
    }
}

extern "C" void kernel_launch(void* const* d_in, const int* in_sizes, int n_in,
                              void* d_out, int out_size, void* d_ws, size_t ws_size,
                              hipStream_t stream) {
    const float* x       = (const float*)d_in[0];
    const float* cond    = (const float*)d_in[1];
    const float* lpe     = (const float*)d_in[2];
    const float* weights = (const float*)d_in[3];
    const float* bias    = (const float*)d_in[4];
    const float* wa_w    = (const float*)d_in[5];
    const float* wa_b    = (const float*)d_in[6];
    const float* ba_w    = (const float*)d_in[7];
    const float* ba_b    = (const float*)d_in[8];
    float* outp = (float*)d_out;
    float* ws   = (float*)d_ws;    // 1024 floats: wadapt | bias*badapt

    adapt_kernel<<<dim3(B_), dim3(256), 0, stream>>>(
        cond, lpe, wa_w, wa_b, ba_w, ba_b, bias, ws);

    conv_kernel<<<dim3(W_/64, H_/32, B_), dim3(256), 0, stream>>>(
        x, weights, ws, outp);
}

// Round 10
// 273.046 us; speedup vs baseline: 1.1413x; 1.0461x over previous
//
#include <hip/hip_runtime.h>

// BatchAdaptiveConv2d via implicit GEMM on bf16 MFMA.
// out[b,o,y,x] = sum_{i,dy,dx} x[b,i,y+dy-1,x+dx-1] * W[i,o,dy,dx]*wadapt[b,i]
//               + bias[o]*badapt[b,o]
// R12: DRAM-granule fix. Falsified so far: occupancy (R5), VMEM instr rate
//  (R9), traffic (R10), store ordering (R11) — all land at 2.6-3.1 TB/s.
//  Invariant: every variant reads/writes ~256B contiguous runs per channel
//  plane (64px tile width) at 256KB plane stride -> poor DRAM row locality.
//  Fix: tile 128px wide x 16 rows (512B runs on BOTH read and store paths),
//  NSLOT=6 window, 4-row steps, 4 iters. Same staging machinery, same
//  minimal traffic, 2 blocks/CU, half the barriers.

#define B_    16
#define CIN   32
#define COUT  32
#define H_    256
#define W_    256
#define EMB2  512

#define TW    128              // tile width in pixels
#define XPX   130              // TW + 2 halo pixels per LDS row
#define PXS   32               // ushorts per pixel (32 ch * bf16)
#define ROWS_ (XPX*PXS)        // 4160 ushorts per row-slot
#define NSLOT 6                // rolling window slots (6-row window, 4-row step)

using short8  = __attribute__((ext_vector_type(8))) short;
using float4v = __attribute__((ext_vector_type(4))) float;
using float4r = __attribute__((ext_vector_type(4))) float;

__device__ __forceinline__ unsigned short f2bf(float f) {
    unsigned u = __builtin_bit_cast(unsigned, f);
    u += 0x7FFFu + ((u >> 16) & 1u);      // RNE
    return (unsigned short)(u >> 16);
}
__device__ __forceinline__ unsigned pk2(float a, float b) {
    return (unsigned)f2bf(a) | ((unsigned)f2bf(b) << 16);
}

// ---------------- kernel 1: adapt coefficients ----------------
// ws[0..511] = wadapt[b][i]; ws[512..1023] = bias[o]*badapt[b][o]
__global__ __launch_bounds__(256) void adapt_kernel(
    const float* __restrict__ cond, const float* __restrict__ lpe,
    const float* __restrict__ wa_w, const float* __restrict__ wa_b,
    const float* __restrict__ ba_w, const float* __restrict__ ba_b,
    const float* __restrict__ bias, float* __restrict__ ws)
{
    __shared__ float iv[EMB2];
    __shared__ float partial[64][4];
    const int b = blockIdx.x;
    const int t = threadIdx.x;

    iv[t]       = cond[b*256 + t];
    iv[t + 256] = lpe[b*256 + t];
    __syncthreads();

    const int out  = t & 63;
    const int part = t >> 6;
    const float* row = (out < 32) ? (wa_w + out*EMB2) : (ba_w + (out-32)*EMB2);
    float s = 0.f;
    #pragma unroll 8
    for (int j = part*128; j < part*128 + 128; ++j) s += iv[j] * row[j];
    partial[out][part] = s;
    __syncthreads();

    if (t < 64) {
        float v = partial[t][0] + partial[t][1] + partial[t][2] + partial[t][3];
        if (t < 32) ws[b*32 + t] = v + wa_b[t];
        else {
            int o = t - 32;
            ws[512 + b*32 + o] = bias[o] * (v + ba_b[o]);
        }
    }
}

// ---------------- kernel 2: MFMA conv ----------------
// grid (W/128, H/16, B); block 256 = 4 waves. Wave w handles output row 4t+w.
__global__ __launch_bounds__(256, 2) void conv_kernel(
    const float* __restrict__ x, const float* __restrict__ weights,
    const float* __restrict__ ws, float* __restrict__ out)
{
    __shared__ __align__(16) unsigned short xbuf[NSLOT * ROWS_];   // 49920 B
    __shared__ __align__(16) unsigned short wbuf[9 * 2 * 64 * 8];  // 18432 B

    const int tid    = threadIdx.x;
    const int lane   = tid & 63;
    const int w      = tid >> 6;        // wave 0..3
    const int ln15   = lane & 15;
    const int kg     = lane >> 4;       // k-group 0..3
    const int xstrip = blockIdx.x * TW;
    const int ystrip = blockIdx.y * 16;
    const int b      = blockIdx.z;

    // ---- scaled weights -> wbuf[tap][ot][lane][j]: lane-consecutive 16B,
    //      conflict-free ds_read_b128 per (tap,ot).
    for (int idx = tid; idx < CIN*COUT*9; idx += 256) {
        int i   = idx / 288;
        int rem = idx - i*288;
        int o   = rem / 9;
        int tap = rem - o*9;
        float v = weights[idx] * ws[b*32 + i];
        wbuf[((tap*2 + (o>>4))*64 + ((i>>3)*16 + (o&15)))*8 + (i&7)] = f2bf(v);
    }

    // ---- helpers ----
    // main-px vector load: 8 channels x 4 consecutive px (8x dwordx4)
    auto ld_main = [&](int gy, int g, int q, float4r (&L)[8]) {
        if ((unsigned)gy < 256u) {
            const float* src = x + (((size_t)(b*CIN + g*8) << 16) + (gy << 8)
                                    + (xstrip + 4*q));
            #pragma unroll
            for (int j = 0; j < 8; ++j)
                L[j] = *(const float4r*)&src[(size_t)j << 16];
        } else {
            #pragma unroll
            for (int j = 0; j < 8; ++j) L[j] = float4r{0.f, 0.f, 0.f, 0.f};
        }
    };
    // register transpose (8ch x 4px -> 4 granules) + swizzled b128 writes.
    // k-stagger (n+q)&3 spreads write banks.
    auto wr_main = [&](int r, int g, int q, const float4r (&L)[8]) {
        unsigned slot = (unsigned)(r + 1) % NSLOT;
        #pragma unroll
        for (int n = 0; n < 4; ++n) {
            int k = (n + q) & 3;
            int p = 4*q + k + 1;                 // LDS pixel index 1..128
            uint4 pk;
            pk.x = pk2(L[0][k], L[1][k]);
            pk.y = pk2(L[2][k], L[3][k]);
            pk.z = pk2(L[4][k], L[5][k]);
            pk.w = pk2(L[6][k], L[7][k]);
            *(uint4*)&xbuf[slot*ROWS_ + p*PXS + ((g ^ ((p >> 1) & 3)) * 8)] = pk;
        }
    };
    // halo: one px, 8 channels, scalar loads (rare)
    auto load8 = [&](int g, int yy, int xx, float (&f)[8]) {
        if (((unsigned)yy < 256u) & ((unsigned)xx < 256u)) {
            const float* src = x + (((size_t)(b*CIN + g*8) << 16) + (yy << 8) + xx);
            #pragma unroll
            for (int j = 0; j < 8; ++j) f[j] = src[(size_t)j << 16];
        } else {
            #pragma unroll
            for (int j = 0; j < 8; ++j) f[j] = 0.f;
        }
    };
    auto packwrite = [&](int r, int p, int g, const float (&f)[8]) {
        unsigned slot = (unsigned)(r + 1) % NSLOT;
        unsigned dst  = slot*ROWS_ + p*PXS + ((g ^ ((p >> 1) & 3)) * 8);
        uint4 pk;
        pk.x = pk2(f[0], f[1]); pk.y = pk2(f[2], f[3]);
        pk.z = pk2(f[4], f[5]); pk.w = pk2(f[6], f[7]);
        *(uint4*)&xbuf[dst] = pk;
    };

    // ---- prologue: direct-stage rows -1..4 (6 rows, slots 0..5) ----
    // main: 6 rows * 4 g * 32 quads = 768 chunks = 3/thread exactly
    #pragma unroll
    for (int k2 = 0; k2 < 3; ++k2) {
        int ci = tid + k2*256;
        int q = ci & 31, g = (ci >> 5) & 3, rr = ci >> 7;       // rr 0..5
        float4r L[8];
        ld_main(ystrip + rr - 1, g, q, L);
        wr_main(rr - 1, g, q, L);
    }
    // halo: 6 rows * 4 g * 2 sides = 48 granules
    if (tid < 48) {
        int s = tid & 1, g = (tid >> 1) & 3, rr = tid >> 3;     // rr 0..5
        int p = s ? (TW + 1) : 0;
        float f[8];
        load8(g, ystrip + rr - 1, xstrip + p - 1, f);
        packwrite(rr - 1, p, g, f);
    }

    // ---- per-lane modulated bias (out = ot*16 + kg*4 + r) ----
    float bm[2][4];
    #pragma unroll
    for (int ot = 0; ot < 2; ++ot)
        #pragma unroll
        for (int r = 0; r < 4; ++r)
            bm[ot][r] = ws[512 + b*32 + ot*16 + kg*4 + r];

    // ---- T14 prefetch state: next 4 rows = 2 chunks/thread + halo ----
    // PMa: rows r0 + (tid>>7)   (rr 0..1)
    // PMb: rows r0 + 2 + (tid>>7) (rr 2..3)   -- named arrays, static idx
    float4r PMa[8], PMb[8];
    float   PH[8];                 // halo: 8 ch x 1 px (tid<32 only)
    auto pf_issue = [&](int r0) {
        {
            int ci = tid;
            int q = ci & 31, g = (ci >> 5) & 3, rr = ci >> 7;   // rr 0..1
            ld_main(ystrip + r0 + rr, g, q, PMa);
        }
        {
            int ci = tid + 256;
            int q = ci & 31, g = (ci >> 5) & 3, rr = ci >> 7;   // rr 2..3
            ld_main(ystrip + r0 + rr, g, q, PMb);
        }
        if (tid < 32) {
            int s = tid & 1, hg = (tid >> 1) & 3, hr = tid >> 3; // hr 0..3
            int p = s ? (TW + 1) : 0;
            load8(hg, ystrip + r0 + hr, xstrip + p - 1, PH);
        }
    };
    auto pf_write = [&](int r0) {
        {
            int ci = tid;
            int q = ci & 31, g = (ci >> 5) & 3, rr = ci >> 7;
            wr_main(r0 + rr, g, q, PMa);
        }
        {
            int ci = tid + 256;
            int q = ci & 31, g = (ci >> 5) & 3, rr = ci >> 7;
            wr_main(r0 + rr, g, q, PMb);
        }
        if (tid < 32) {
            int s = tid & 1, hg = (tid >> 1) & 3, hr = tid >> 3;
            int p = s ? (TW + 1) : 0;
            packwrite(r0 + hr, p, hg, PH);
        }
    };

    pf_issue(5);                                // rows 5..8 for iter 1

    // prologue barrier: LDS writes visible; prefetch loads stay in flight.
    asm volatile("s_waitcnt lgkmcnt(0)" ::: "memory");
    __builtin_amdgcn_s_barrier();
    asm volatile("" ::: "memory");

    for (int t = 0; t < 4; ++t) {
        const int orow = 4*t + w;               // this wave's output row
        const int gy   = ystrip + orow;

        float4v acc[8][2];
        #pragma unroll
        for (int c = 0; c < 8; ++c) {
            acc[c][0] = float4v{0.f, 0.f, 0.f, 0.f};
            acc[c][1] = float4v{0.f, 0.f, 0.f, 0.f};
        }

        #pragma unroll
        for (int dy = 0; dy < 3; ++dy) {
            // row orow+dy-1 lives in slot (orow+dy) % NSLOT  (slot(r)=(r+1)%NSLOT)
            const int rowbase = (int)((unsigned)(orow + dy) % NSLOT) * ROWS_;
            #pragma unroll
            for (int dx = 0; dx < 3; ++dx) {
                const int tap = dy*3 + dx;
                short8 a0 = *(const short8*)&wbuf[((tap*2 + 0)*64 + lane)*8];
                short8 a1 = *(const short8*)&wbuf[((tap*2 + 1)*64 + lane)*8];
                #pragma unroll
                for (int c = 0; c < 8; ++c) {
                    int p = c*16 + dx + ln15;               // LDS pixel index
                    int a = rowbase + p*PXS + ((kg ^ ((p >> 1) & 3)) * 8);
                    short8 xf = *(const short8*)&xbuf[a];
                    acc[c][0] = __builtin_amdgcn_mfma_f32_16x16x32_bf16(
                                    a0, xf, acc[c][0], 0, 0, 0);
                    acc[c][1] = __builtin_amdgcn_mfma_f32_16x16x32_bf16(
                                    a1, xf, acc[c][1], 0, 0, 0);
                }
            }
        }

        // post-compute barrier: all waves' LDS window reads done.
        asm volatile("s_waitcnt lgkmcnt(0)" ::: "memory");
        __builtin_amdgcn_s_barrier();
        asm volatile("" ::: "memory");

        // prefetch first (loads stay older than this iter's stores)
        if (t < 3) {
            pf_write(4*t + 5);
            if (t < 2) pf_issue(4*t + 9);
        }

        asm volatile("" ::: "memory");

        // epilogue stores: D row(out) = kg*4 + r, col(pixel) = ln15.
        // 8 c-chunks close in time -> 512B runs per (ch,row).
        #pragma unroll
        for (int c = 0; c < 8; ++c) {
            const int xcol = xstrip + c*16 + ln15;
            #pragma unroll
            for (int ot = 0; ot < 2; ++ot) {
                const int obase = ot*16 + kg*4;
                #pragma unroll
                for (int r = 0; r < 4; ++r) {
                    out[((size_t)(b*COUT + obase + r)*256 + gy)*256 + xcol] =
                        acc[c][ot][r] + bm[ot][r];
                }
            }
        }

        if (t < 3) {
            // staging barrier: ds_writes visible; stores/loads NOT drained.
            asm volatile("s_waitcnt lgkmcnt(0)" ::: "memory");
            __builtin_amdgcn_s_barrier();
            asm volatile("" ::: "memory");
        }
    }
}

extern "C" void kernel_launch(void* const* d_in, const int* in_sizes, int n_in,
                              void* d_out, int out_size, void* d_ws, size_t ws_size,
                              hipStream_t stream) {
    const float* x       = (const float*)d_in[0];
    const float* cond    = (const float*)d_in[1];
    const float* lpe     = (const float*)d_in[2];
    const float* weights = (const float*)d_in[3];
    const float* bias    = (const float*)d_in[4];
    const float* wa_w    = (const float*)d_in[5];
    const float* wa_b    = (const float*)d_in[6];
    const float* ba_w    = (const float*)d_in[7];
    const float* ba_b    = (const float*)d_in[8];
    float* outp = (float*)d_out;
    float* ws   = (float*)d_ws;    // 1024 floats: wadapt | bias*badapt

    adapt_kernel<<<dim3(B_), dim3(256), 0, stream>>>(
        cond, lpe, wa_w, wa_b, ba_w, ba_b, bias, ws);

    conv_kernel<<<dim3(W_/TW, H_/16, B_), dim3(256), 0, stream>>>(
        x, weights, ws, outp);
}